// Round 6
// baseline (442.649 us; speedup 1.0000x reference)
//
#include <hip/hip_runtime.h>
#include <hip/hip_bf16.h>

typedef __hip_bfloat16 bf16;
typedef __attribute__((ext_vector_type(8))) short short8;
typedef __attribute__((ext_vector_type(4))) float fl4;

#define Bn 4
#define Cn 512
#define C8n 64
#define Nn 4096
#define XKS 536   // qkv LDS k-stride (bf16): 512+24 -> <=2-way banks, 16B-aligned rows

union BfU { bf16 h; unsigned short u; };
__device__ __forceinline__ unsigned short f2b(float f) { BfU c; c.h = __float2bfloat16(f); return c.u; }
__device__ __forceinline__ float b2f_(unsigned short u) { BfU c; c.u = u; return __bfloat162float(c.h); }

#define MFMA16(a, b, c) __builtin_amdgcn_mfma_f32_16x16x32_bf16(a, b, c, 0, 0, 0)
// 16-lane-row rotate via DPP (VALU pipe, no LDS)
#define ROR1(x) __uint_as_float(__builtin_amdgcn_update_dpp(0, (int)__float_as_uint(x), 0x121, 0xF, 0xF, true))
#define ROR2(x) __uint_as_float(__builtin_amdgcn_update_dpp(0, (int)__float_as_uint(x), 0x122, 0xF, 0xF, true))
#define ROR4(x) __uint_as_float(__builtin_amdgcn_update_dpp(0, (int)__float_as_uint(x), 0x124, 0xF, 0xF, true))
#define ROR8(x) __uint_as_float(__builtin_amdgcn_update_dpp(0, (int)__float_as_uint(x), 0x128, 0xF, 0xF, true))

// ---------------- prep: W concat -> hi/lo bf16 [640][512], bias concat ----------------
__global__ __launch_bounds__(128) void prep_w(
    const float* __restrict__ Wq, const float* __restrict__ bq,
    const float* __restrict__ Wk, const float* __restrict__ bk,
    const float* __restrict__ Wv, const float* __restrict__ bv,
    bf16* __restrict__ whi, bf16* __restrict__ wlo, float* __restrict__ bcat) {
  int row = blockIdx.x;
  int t = threadIdx.x;
  const float* src = (row < 64) ? Wq + (size_t)row * Cn
                   : (row < 128) ? Wk + (size_t)(row - 64) * Cn
                                 : Wv + (size_t)(row - 128) * Cn;
  float4 v = *(const float4*)(src + t * 4);
  unsigned short h0 = f2b(v.x), h1 = f2b(v.y), h2 = f2b(v.z), h3 = f2b(v.w);
  unsigned short l0 = f2b(v.x - b2f_(h0)), l1 = f2b(v.y - b2f_(h1));
  unsigned short l2 = f2b(v.z - b2f_(h2)), l3 = f2b(v.w - b2f_(h3));
  uint2 hu, lu;
  hu.x = h0 | ((unsigned)h1 << 16); hu.y = h2 | ((unsigned)h3 << 16);
  lu.x = l0 | ((unsigned)l1 << 16); lu.y = l2 | ((unsigned)l3 << 16);
  *(uint2*)(whi + (size_t)row * Cn + t * 4) = hu;
  *(uint2*)(wlo + (size_t)row * Cn + t * 4) = lu;
  if (t == 0)
    bcat[row] = (row < 64) ? bq[row] : (row < 128) ? bk[row - 64] : bv[row - 128];
}

// ---------------- fused QKV projection via MFMA ----------------
// 512 thr = 8 waves; wave owns 5 m-tiles (m=(j*8+w)*16) -> live set ~116 VGPR, no spill.
// j=0: waves 0-3 = Q tiles, waves 4-7 = K tiles; j=1..4 = V channels.
__global__ __launch_bounds__(512, 4) void qkv_proj(
    const float* __restrict__ x, const bf16* __restrict__ whi, const bf16* __restrict__ wlo,
    const float* __restrict__ bcat,
    bf16* __restrict__ qhi, bf16* __restrict__ qlo,
    bf16* __restrict__ khi, bf16* __restrict__ klo, bf16* __restrict__ vh) {
  __shared__ bf16 xh[32 * XKS];
  __shared__ bf16 xl[32 * XKS];
  int t = threadIdx.x;
  int b = blockIdx.x >> 7;
  int n0 = (blockIdx.x & 127) << 5;

  // stage x: hi/lo conversion once; packed b32 LDS writes
  const float* xb = x + (size_t)b * Cn * Nn + n0;
  #pragma unroll
  for (int i = 0; i < 4; ++i) {
    int idx = t + i * 512;
    int ng = idx & 7, cp = idx >> 3;
    int c0 = cp * 2;
    float4 va = *(const float4*)(xb + (size_t)c0 * Nn + ng * 4);
    float4 vb2 = *(const float4*)(xb + (size_t)(c0 + 1) * Nn + ng * 4);
    float a_[4] = { va.x, va.y, va.z, va.w };
    float b_[4] = { vb2.x, vb2.y, vb2.z, vb2.w };
    #pragma unroll
    for (int k = 0; k < 4; ++k) {
      int n = ng * 4 + k;
      unsigned short ha = f2b(a_[k]), hb = f2b(b_[k]);
      unsigned short la = f2b(a_[k] - b2f_(ha)), lb = f2b(b_[k] - b2f_(hb));
      *(unsigned*)(&xh[n * XKS + c0]) = (unsigned)ha | ((unsigned)hb << 16);
      *(unsigned*)(&xl[n * XKS + c0]) = (unsigned)la | ((unsigned)lb << 16);
    }
  }

  int w = t >> 6, lane = t & 63, col = lane & 15, quad = lane >> 4;

  fl4 acc[5][2];
  #pragma unroll
  for (int j = 0; j < 5; ++j) {
    int m = (j * 8 + w) * 16 + quad * 4;
    fl4 bi = { bcat[m], bcat[m + 1], bcat[m + 2], bcat[m + 3] };
    acc[j][0] = bi; acc[j][1] = bi;
  }
  __syncthreads();

  for (int kk = 0; kk < 16; ++kk) {
    short8 ah[5], al[5];
    #pragma unroll
    for (int j = 0; j < 5; ++j) {
      size_t off = (size_t)(((j * 8 + w) * 16 + col)) * Cn + kk * 32 + quad * 8;
      ah[j] = *(const short8*)(whi + off);
      al[j] = *(const short8*)(wlo + off);
    }
    short8 bh[2], bl[2];
    #pragma unroll
    for (int ns = 0; ns < 2; ++ns) {
      int o = (ns * 16 + col) * XKS + kk * 32 + quad * 8;
      bh[ns] = *(const short8*)(&xh[o]);
      bl[ns] = *(const short8*)(&xl[o]);
    }
    #pragma unroll
    for (int j = 0; j < 5; ++j) {
      #pragma unroll
      for (int ns = 0; ns < 2; ++ns) {
        acc[j][ns] = MFMA16(ah[j], bh[ns], acc[j][ns]);
        acc[j][ns] = MFMA16(al[j], bh[ns], acc[j][ns]);
        acc[j][ns] = MFMA16(ah[j], bl[ns], acc[j][ns]);
      }
    }
  }

  // ---- V epilogue: j=1..4 -> channels 0..511 ----
  #pragma unroll
  for (int j = 1; j < 5; ++j) {
    int c = (j * 8 + w) * 16 - 128 + quad * 4;
    #pragma unroll
    for (int ns = 0; ns < 2; ++ns) {
      #pragma unroll
      for (int r = 0; r < 4; ++r) {
        vh[((size_t)b * Cn + c + r) * Nn + n0 + ns * 16 + col] =
            __float2bfloat16(acc[j][ns][r]);
      }
    }
  }

  // ---- Q/K epilogue: transpose via LDS (reuse xh), pack hi/lo [b][n][64] ----
  __syncthreads();
  float* qbuf = (float*)xh;               // [32][65]
  float* kbuf = qbuf + 32 * 65;           // [32][65]
  {
    float* dst = (w < 4) ? qbuf : kbuf;
    int ch = (w & 3) * 16 + quad * 4;
    #pragma unroll
    for (int ns = 0; ns < 2; ++ns) {
      #pragma unroll
      for (int r = 0; r < 4; ++r)
        dst[(ns * 16 + col) * 65 + ch + r] = acc[0][ns][r];
    }
  }
  __syncthreads();
  {
    int n = t >> 4, g = t & 15;
    int och = g * 4;
    size_t orow = ((size_t)b * Nn + n0 + n) * 64 + och;
    float v[4];
    unsigned short h[4], l[4];
    #pragma unroll
    for (int i = 0; i < 4; ++i) v[i] = qbuf[n * 65 + och + i];
    #pragma unroll
    for (int i = 0; i < 4; ++i) { h[i] = f2b(v[i]); l[i] = f2b(v[i] - b2f_(h[i])); }
    uint2 hu, lu;
    hu.x = h[0] | ((unsigned)h[1] << 16); hu.y = h[2] | ((unsigned)h[3] << 16);
    lu.x = l[0] | ((unsigned)l[1] << 16); lu.y = l[2] | ((unsigned)l[3] << 16);
    *(uint2*)(qhi + orow) = hu;
    *(uint2*)(qlo + orow) = lu;
    #pragma unroll
    for (int i = 0; i < 4; ++i) v[i] = kbuf[n * 65 + och + i];
    #pragma unroll
    for (int i = 0; i < 4; ++i) { h[i] = f2b(v[i]); l[i] = f2b(v[i] - b2f_(h[i])); }
    hu.x = h[0] | ((unsigned)h[1] << 16); hu.y = h[2] | ((unsigned)h[3] << 16);
    lu.x = l[0] | ((unsigned)l[1] << 16); lu.y = l[2] | ((unsigned)l[3] << 16);
    *(uint2*)(khi + orow) = hu;
    *(uint2*)(klo + orow) = lu;
  }
}

// ---------------- MFMA flash attention: producer/consumer waves ----------------
// 768 thr = 12 waves: 4 S-waves (QK + in-reg softmax), 8 O-waves (PV deferred 1 tile).
// 2x-unrolled tile loop: V loads double-buffered in regs, issued at TOP of O-path so
// the compiler's vmcnt(0)-before-barrier drain is covered by ~1 iter of MFMA work.
#define ATTN_ITER(TILE, BUF, VLOAD, VUSE)                                        \
  {                                                                              \
    __syncthreads();                                                             \
    if (t < 512) {                                                               \
      *(uint4*)(kd + ((BUF) ^ 1) * 4608) = kpre;                                 \
      int jn = ((TILE) + 2 < 128 ? (TILE) + 2 : 127) << 5;                       \
      kpre = *(const uint4*)(ksrc + kgbase + (size_t)jn * 64);                   \
    }                                                                            \
    if (w < 4) {                                                                 \
      const bf16* kb = kths + (BUF) * 4608;                                      \
      const bf16* kbl = kb + 2304;                                               \
      short8 khA0 = *(const short8*)(kb + col * 72 + quad * 8);                  \
      short8 khA1 = *(const short8*)(kb + col * 72 + quad * 8 + 32);             \
      short8 khB0 = *(const short8*)(kb + (16 + col) * 72 + quad * 8);           \
      short8 khB1 = *(const short8*)(kb + (16 + col) * 72 + quad * 8 + 32);      \
      short8 klA0 = *(const short8*)(kbl + col * 72 + quad * 8);                 \
      short8 klA1 = *(const short8*)(kbl + col * 72 + quad * 8 + 32);            \
      short8 klB0 = *(const short8*)(kbl + (16 + col) * 72 + quad * 8);          \
      short8 klB1 = *(const short8*)(kbl + (16 + col) * 72 + quad * 8 + 32);     \
      fl4 c1 = MFMA16(qh0, khA0, z);                                             \
      fl4 c2 = MFMA16(ql0, khA0, z);                                             \
      fl4 c3 = MFMA16(qh0, klA0, z);                                             \
      fl4 d1 = MFMA16(qh0, khB0, z);                                             \
      fl4 d2 = MFMA16(ql0, khB0, z);                                             \
      fl4 d3 = MFMA16(qh0, klB0, z);                                             \
      c1 = MFMA16(qh1, khA1, c1);                                                \
      c2 = MFMA16(ql1, khA1, c2);                                                \
      c3 = MFMA16(qh1, klA1, c3);                                                \
      d1 = MFMA16(qh1, khB1, d1);                                                \
      d2 = MFMA16(ql1, khB1, d2);                                                \
      d3 = MFMA16(qh1, klB1, d3);                                                \
      fl4 sA = (c1 + c2) + c3;                                                   \
      fl4 sB = (d1 + d2) + d3;                                                   \
      _Pragma("unroll")                                                          \
      for (int r = 0; r < 4; ++r) {                                              \
        float mt_ = fmaxf(sA[r], sB[r]);                                         \
        mt_ = fmaxf(mt_, ROR1(mt_)); mt_ = fmaxf(mt_, ROR2(mt_));                \
        mt_ = fmaxf(mt_, ROR4(mt_)); mt_ = fmaxf(mt_, ROR8(mt_));                \
        float mnew = fmaxf(mreg[r], mt_);                                        \
        float al = __expf(mreg[r] - mnew);                                       \
        float pA = __expf(sA[r] - mnew);                                         \
        float pB = __expf(sB[r] - mnew);                                         \
        float s = pA + pB;                                                       \
        s += ROR1(s); s += ROR2(s); s += ROR4(s); s += ROR8(s);                  \
        lreg[r] = lreg[r] * al + s;                                              \
        mreg[r] = mnew;                                                          \
        int i = it * 16 + quad * 4 + r;                                          \
        pt[(BUF) * 2560 + i * 40 + col] = __float2bfloat16(pA);                  \
        pt[(BUF) * 2560 + i * 40 + 16 + col] = __float2bfloat16(pB);             \
        if (col == 0) alpha_s[(BUF) * 64 + i] = al;                              \
      }                                                                          \
    } else {                                                                     \
      const bf16* vj = vbase + ((TILE) << 5);                                    \
      VLOAD[0] = *(const short8*)(vj);                                           \
      VLOAD[1] = *(const short8*)(vj + (size_t)16 * Nn);                         \
      VLOAD[2] = *(const short8*)(vj + (size_t)32 * Nn);                         \
      VLOAD[3] = *(const short8*)(vj + (size_t)48 * Nn);                         \
      if ((TILE) > 0) {                                                          \
        int pb_ = (BUF) ^ 1;                                                     \
        float av[4];                                                             \
        _Pragma("unroll")                                                        \
        for (int nt = 0; nt < 4; ++nt) av[nt] = alpha_s[pb_ * 64 + nt * 16 + col]; \
        bool nr = (av[0] != 1.f) | (av[1] != 1.f) | (av[2] != 1.f) | (av[3] != 1.f); \
        if (__ballot(nr)) {                                                      \
          _Pragma("unroll")                                                      \
          for (int mt = 0; mt < 4; ++mt)                                         \
            _Pragma("unroll")                                                    \
            for (int nt = 0; nt < 4; ++nt) acc[mt][nt] *= av[nt];                \
        }                                                                        \
        short8 pb[4];                                                            \
        _Pragma("unroll")                                                        \
        for (int nt = 0; nt < 4; ++nt)                                           \
          pb[nt] = *(const short8*)(&pt[pb_ * 2560 + (nt * 16 + col) * 40 + quad * 8]); \
        _Pragma("unroll")                                                        \
        for (int nt = 0; nt < 4; ++nt) {                                         \
          acc[0][nt] = MFMA16(VUSE[0], pb[nt], acc[0][nt]);                      \
          acc[1][nt] = MFMA16(VUSE[1], pb[nt], acc[1][nt]);                      \
          acc[2][nt] = MFMA16(VUSE[2], pb[nt], acc[2][nt]);                      \
          acc[3][nt] = MFMA16(VUSE[3], pb[nt], acc[3][nt]);                      \
        }                                                                        \
      }                                                                          \
    }                                                                            \
  }

__global__ __launch_bounds__(768, 3) void attn(
    const bf16* __restrict__ qhi_g, const bf16* __restrict__ qlo_g,
    const bf16* __restrict__ khi_g, const bf16* __restrict__ klo_g,
    const bf16* __restrict__ vh, const float* __restrict__ x,
    const float* __restrict__ gamma, float* __restrict__ out) {
  __shared__ bf16 kths[2 * 2 * 32 * 72]; // [buf][hl][j][72]
  __shared__ bf16 pt[2 * 64 * 40];       // [buf][i][j], j-stride 40
  __shared__ float alpha_s[2 * 64];
  __shared__ float lfin[64];

  int t = threadIdx.x;
  int w = t >> 6;
  int lane = t & 63;
  int col = lane & 15;
  int quad = lane >> 4;

  int blk = blockIdx.x;
  int xcd = blk & 7;
  int b = xcd >> 1;
  int itile = ((xcd & 1) << 5) + (blk >> 3);
  int i0 = itile << 6;

  fl4 z = {0.f, 0.f, 0.f, 0.f};

  // ---- K staging setup (threads 0-511: 256 hi + 256 lo) ----
  const bf16* ksrc = (t < 256) ? khi_g : klo_g;
  int hl = (t < 256) ? 0 : 1;
  int ki = t & 255, kj = ki >> 3, koc = ki & 7;
  size_t kgbase = ((size_t)b * Nn + kj) * 64 + koc * 8;
  bf16* kd = kths + hl * 2304 + kj * 72 + koc * 8;
  uint4 kpre;
  if (t < 512) {
    kpre = *(const uint4*)(ksrc + kgbase);            // tile 0
    *(uint4*)kd = kpre;                               // -> buf 0
    kpre = *(const uint4*)(ksrc + kgbase + 32 * 64);  // tile 1
  }

  // ---- S-wave state ----
  int it = w;
  short8 qh0, qh1, ql0, ql1;
  float mreg[4], lreg[4];
  if (w < 4) {
    size_t qrow = ((size_t)b * Nn + i0 + it * 16 + col) * 64 + quad * 8;
    qh0 = *(const short8*)(qhi_g + qrow);
    qh1 = *(const short8*)(qhi_g + qrow + 32);
    ql0 = *(const short8*)(qlo_g + qrow);
    ql1 = *(const short8*)(qlo_g + qrow + 32);
    #pragma unroll
    for (int r = 0; r < 4; ++r) { mreg[r] = -3.0e38f; lreg[r] = 0.f; }
  }

  // ---- O-wave state ----
  int ow = w - 4, ch0 = ow * 64;
  const bf16* vbase = vh + ((size_t)b * Cn + ch0 + col) * Nn + quad * 8;
  fl4 acc[4][4];
  #pragma unroll
  for (int mt = 0; mt < 4; ++mt)
    #pragma unroll
    for (int nt = 0; nt < 4; ++nt) acc[mt][nt] = z;
  short8 vaA[4], vaB[4];

  for (int tp = 0; tp < 64; ++tp) {
    ATTN_ITER(tp * 2, 0, vaA, vaB)
    ATTN_ITER(tp * 2 + 1, 1, vaB, vaA)
  }

  // ---- finalize ----
  if (w < 4 && col == 0) {
    #pragma unroll
    for (int r = 0; r < 4; ++r) lfin[it * 16 + quad * 4 + r] = lreg[r];
  }
  __syncthreads();

  if (w >= 4) {
    // PV(127): va = vaB (loaded at tile 127), P/alpha buf 1
    float av[4];
    #pragma unroll
    for (int nt = 0; nt < 4; ++nt) av[nt] = alpha_s[64 + nt * 16 + col];
    bool nr = (av[0] != 1.f) | (av[1] != 1.f) | (av[2] != 1.f) | (av[3] != 1.f);
    if (__ballot(nr)) {
      #pragma unroll
      for (int mt = 0; mt < 4; ++mt)
        #pragma unroll
        for (int nt = 0; nt < 4; ++nt) acc[mt][nt] *= av[nt];
    }
    short8 pb[4];
    #pragma unroll
    for (int nt = 0; nt < 4; ++nt)
      pb[nt] = *(const short8*)(&pt[2560 + (nt * 16 + col) * 40 + quad * 8]);
    #pragma unroll
    for (int nt = 0; nt < 4; ++nt) {
      acc[0][nt] = MFMA16(vaB[0], pb[nt], acc[0][nt]);
      acc[1][nt] = MFMA16(vaB[1], pb[nt], acc[1][nt]);
      acc[2][nt] = MFMA16(vaB[2], pb[nt], acc[2][nt]);
      acc[3][nt] = MFMA16(vaB[3], pb[nt], acc[3][nt]);
    }

    float gm = gamma[0];
    float linv[4];
    #pragma unroll
    for (int nt = 0; nt < 4; ++nt) linv[nt] = 1.f / lfin[nt * 16 + col];
    #pragma unroll
    for (int mt = 0; mt < 4; ++mt) {
      int c = ch0 + mt * 16 + quad * 4;
      #pragma unroll
      for (int r = 0; r < 4; ++r) {
        size_t rowoff = ((size_t)b * Cn + c + r) * Nn + i0;
        #pragma unroll
        for (int nt = 0; nt < 4; ++nt) {
          size_t off = rowoff + nt * 16 + col;
          out[off] = gm * (acc[mt][nt][r] * linv[nt]) + x[off];
        }
      }
    }
  }
}

extern "C" void kernel_launch(void* const* d_in, const int* in_sizes, int n_in,
                              void* d_out, int out_size, void* d_ws, size_t ws_size,
                              hipStream_t stream) {
  const float* x     = (const float*)d_in[0];
  const float* Wq    = (const float*)d_in[1];
  const float* bq    = (const float*)d_in[2];
  const float* Wk    = (const float*)d_in[3];
  const float* bk    = (const float*)d_in[4];
  const float* Wv    = (const float*)d_in[5];
  const float* bv    = (const float*)d_in[6];
  const float* gamma = (const float*)d_in[7];
  float* out = (float*)d_out;

  size_t qkN = (size_t)Bn * Nn * 64;            // 1M elems = 2 MB each
  bf16* qhi = (bf16*)d_ws;
  bf16* qlo = qhi + qkN;
  bf16* khi = qlo + qkN;
  bf16* klo = khi + qkN;
  bf16* vh  = klo + qkN;                        // 16 MB
  bf16* whi = vh + (size_t)Bn * Cn * Nn;        // 640 KB
  bf16* wlo = whi + (size_t)640 * Cn;           // 640 KB
  float* bcat = (float*)(wlo + (size_t)640 * Cn);

  prep_w<<<dim3(640), dim3(128), 0, stream>>>(Wq, bq, Wk, bk, Wv, bv, whi, wlo, bcat);
  qkv_proj<<<dim3(Bn * 128), dim3(512), 0, stream>>>(x, whi, wlo, bcat,
                                                     qhi, qlo, khi, klo, vh);
  attn<<<dim3(256), dim3(768), 0, stream>>>(qhi, qlo, khi, klo, vh, x, gamma, out);
}

// Round 7
// 312.002 us; speedup vs baseline: 1.4187x; 1.4187x over previous
//
#include <hip/hip_runtime.h>
#include <hip/hip_bf16.h>

typedef __hip_bfloat16 bf16;
typedef __attribute__((ext_vector_type(8))) short short8;
typedef __attribute__((ext_vector_type(4))) float fl4;

#define Bn 4
#define Cn 512
#define C8n 64
#define Nn 4096

union BfU { bf16 h; unsigned short u; };
__device__ __forceinline__ unsigned short f2b(float f) { BfU c; c.h = __float2bfloat16(f); return c.u; }
__device__ __forceinline__ float b2f_(unsigned short u) { BfU c; c.u = u; return __bfloat162float(c.h); }

#define MFMA16(a, b, c) __builtin_amdgcn_mfma_f32_16x16x32_bf16(a, b, c, 0, 0, 0)
// 16-lane-row rotate via DPP (VALU pipe, no LDS)
#define ROR1(x) __uint_as_float(__builtin_amdgcn_update_dpp(0, (int)__float_as_uint(x), 0x121, 0xF, 0xF, true))
#define ROR2(x) __uint_as_float(__builtin_amdgcn_update_dpp(0, (int)__float_as_uint(x), 0x122, 0xF, 0xF, true))
#define ROR4(x) __uint_as_float(__builtin_amdgcn_update_dpp(0, (int)__float_as_uint(x), 0x124, 0xF, 0xF, true))
#define ROR8(x) __uint_as_float(__builtin_amdgcn_update_dpp(0, (int)__float_as_uint(x), 0x128, 0xF, 0xF, true))

typedef const __attribute__((address_space(1))) char* gas1_t;
typedef __attribute__((address_space(3))) char* las3_t;
#define GL16(gp, lp) __builtin_amdgcn_global_load_lds((gas1_t)(gp), (las3_t)(lp), 16, 0, 0)

// ---------------- prep: W concat -> hi/lo bf16 [640][512], bias concat ----------------
__global__ __launch_bounds__(128) void prep_w(
    const float* __restrict__ Wq, const float* __restrict__ bq,
    const float* __restrict__ Wk, const float* __restrict__ bk,
    const float* __restrict__ Wv, const float* __restrict__ bv,
    bf16* __restrict__ whi, bf16* __restrict__ wlo, float* __restrict__ bcat) {
  int row = blockIdx.x;
  int t = threadIdx.x;
  const float* src = (row < 64) ? Wq + (size_t)row * Cn
                   : (row < 128) ? Wk + (size_t)(row - 64) * Cn
                                 : Wv + (size_t)(row - 128) * Cn;
  float4 v = *(const float4*)(src + t * 4);
  unsigned short h0 = f2b(v.x), h1 = f2b(v.y), h2 = f2b(v.z), h3 = f2b(v.w);
  unsigned short l0 = f2b(v.x - b2f_(h0)), l1 = f2b(v.y - b2f_(h1));
  unsigned short l2 = f2b(v.z - b2f_(h2)), l3 = f2b(v.w - b2f_(h3));
  uint2 hu, lu;
  hu.x = h0 | ((unsigned)h1 << 16); hu.y = h2 | ((unsigned)h3 << 16);
  lu.x = l0 | ((unsigned)l1 << 16); lu.y = l2 | ((unsigned)l3 << 16);
  *(uint2*)(whi + (size_t)row * Cn + t * 4) = hu;
  *(uint2*)(wlo + (size_t)row * Cn + t * 4) = lu;
  if (t == 0)
    bcat[row] = (row < 64) ? bq[row] : (row < 128) ? bk[row - 64] : bv[row - 128];
}

// ---------------- prep_x: x[b][c][n] f32 -> x^T hi/lo bf16 [b][n][c] ----------------
// 32x32 tiles via LDS. Output lands in d_out (scratch until attn overwrites it).
__global__ __launch_bounds__(256) void prep_x(
    const float* __restrict__ x, bf16* __restrict__ xth, bf16* __restrict__ xtl) {
  __shared__ float ts[32][33];
  int t = threadIdx.x;
  int gid = blockIdx.x;
  int b = gid >> 11;
  int rem = gid & 2047;
  int ct = rem >> 7, nt = rem & 127;
  int c0 = ct << 5, n0 = nt << 5;
  {
    int cl = t >> 3, nf = t & 7;
    float4 v = *(const float4*)(x + ((size_t)b * Cn + c0 + cl) * Nn + n0 + nf * 4);
    ts[cl][nf * 4 + 0] = v.x; ts[cl][nf * 4 + 1] = v.y;
    ts[cl][nf * 4 + 2] = v.z; ts[cl][nf * 4 + 3] = v.w;
  }
  __syncthreads();
  {
    int nl = t >> 3, cg = t & 7;
    float a0 = ts[cg * 4 + 0][nl], a1 = ts[cg * 4 + 1][nl];
    float a2 = ts[cg * 4 + 2][nl], a3 = ts[cg * 4 + 3][nl];
    unsigned short h0 = f2b(a0), h1 = f2b(a1), h2 = f2b(a2), h3 = f2b(a3);
    unsigned short l0 = f2b(a0 - b2f_(h0)), l1 = f2b(a1 - b2f_(h1));
    unsigned short l2 = f2b(a2 - b2f_(h2)), l3 = f2b(a3 - b2f_(h3));
    uint2 hu, lu;
    hu.x = h0 | ((unsigned)h1 << 16); hu.y = h2 | ((unsigned)h3 << 16);
    lu.x = l0 | ((unsigned)l1 << 16); lu.y = l2 | ((unsigned)l3 << 16);
    size_t off = ((size_t)b * Nn + n0 + nl) * Cn + c0 + cg * 4;
    *(uint2*)(xth + off) = hu;
    *(uint2*)(xtl + off) = lu;
  }
}

// ---------------- qkv GEMM: C[640][128-ntile] = Whl[640][512] x xhl^T, K'=1536 ----------------
// m97 structure: 128x128 tile, 4 waves (2x2), BK=32, double-buffered global_load_lds(16B).
// K-planes: p0 = Wh*xh, p1 = Wh*xl, p2 = Wl*xh  -> f32-accurate (same math as R4-R6).
// LDS tile layout [kquad][row][8] bf16 (dense, lane-linear for global_load_lds; b128 frag
// reads hit the bandwidth floor, no super-linear conflicts).
__global__ __launch_bounds__(256, 3) void qkv_gemm(
    const bf16* __restrict__ whi, const float* __restrict__ bcat,
    const bf16* __restrict__ xth,
    bf16* __restrict__ qhi, bf16* __restrict__ qlo,
    bf16* __restrict__ khi, bf16* __restrict__ klo, bf16* __restrict__ vh) {
  __shared__ char smem[32768];   // [buf][A 8KB | B 8KB]
  int t = threadIdx.x;
  int w = t >> 6, lane = t & 63, col = lane & 15, quad = lane >> 4;
  int wm = w & 1, wn = w >> 1;

  int gid = blockIdx.x;
  int b = gid / 160;
  int r2 = gid - b * 160;
  int mb = r2 >> 5;            // 0..4 (0 = Q|K rows, 1..4 = V rows)
  int nb = r2 & 31;
  int m0 = mb << 7, n0 = nb << 7;

  const char* wB = (const char*)whi;
  const char* xB = (const char*)xth;
  // per-lane global byte offsets (row-major, 1024 B/row, chunk w*16 within 64-B k-slice)
  size_t aRow0 = ((size_t)(m0 + lane)) * 1024 + w * 16;
  size_t aRow1 = ((size_t)(m0 + 64 + lane)) * 1024 + w * 16;
  size_t bRow0 = ((size_t)b * Nn + n0 + lane) * 1024 + w * 16;
  size_t bRow1 = bRow0 + (size_t)64 * 1024;
  const size_t WLO_OFF = (size_t)640 * 1024;        // wlo = whi + 640*512 bf16
  const size_t XTL_OFF = (size_t)Bn * Nn * 1024;    // xtl = xth + 4*4096*512 bf16

  #define STAGE(G, BUF)                                                        \
    {                                                                          \
      int p_ = (G) >> 4;                                                       \
      size_t ka_ = (size_t)((G) & 15) * 64 + (p_ == 2 ? WLO_OFF : 0);          \
      size_t kb_ = (size_t)((G) & 15) * 64 + (p_ == 1 ? XTL_OFF : 0);          \
      char* L_ = smem + (BUF) * 16384;                                         \
      GL16(wB + aRow0 + ka_, L_ + w * 2048);                                   \
      GL16(wB + aRow1 + ka_, L_ + w * 2048 + 1024);                            \
      GL16(xB + bRow0 + kb_, L_ + 8192 + w * 2048);                            \
      GL16(xB + bRow1 + kb_, L_ + 8192 + w * 2048 + 1024);                     \
    }

  fl4 z = {0.f, 0.f, 0.f, 0.f};
  fl4 acc[4][4];
  #pragma unroll
  for (int mt = 0; mt < 4; ++mt)
    #pragma unroll
    for (int nt = 0; nt < 4; ++nt) acc[mt][nt] = z;

  STAGE(0, 0)
  for (int g = 0; g < 48; ++g) {
    __syncthreads();
    if (g < 47) STAGE(g + 1, (g + 1) & 1)
    const bf16* L = (const bf16*)(smem + (g & 1) * 16384);
    const bf16* Ab = L;
    const bf16* Bb = L + 4096;
    short8 af[4], bfr[4];
    #pragma unroll
    for (int mt = 0; mt < 4; ++mt)
      af[mt] = *(const short8*)(Ab + quad * 1024 + (wm * 64 + mt * 16 + col) * 8);
    #pragma unroll
    for (int nt = 0; nt < 4; ++nt)
      bfr[nt] = *(const short8*)(Bb + quad * 1024 + (wn * 64 + nt * 16 + col) * 8);
    #pragma unroll
    for (int mt = 0; mt < 4; ++mt)
      #pragma unroll
      for (int nt = 0; nt < 4; ++nt)
        acc[mt][nt] = MFMA16(af[mt], bfr[nt], acc[mt][nt]);
  }
  __syncthreads();

  // bias
  #pragma unroll
  for (int mt = 0; mt < 4; ++mt)
    #pragma unroll
    for (int r = 0; r < 4; ++r) {
      float bb = bcat[m0 + wm * 64 + mt * 16 + quad * 4 + r];
      #pragma unroll
      for (int nt = 0; nt < 4; ++nt) acc[mt][nt][r] += bb;
    }

  if (mb > 0) {
    // ---- V epilogue: bf16 scatter stores ----
    #pragma unroll
    for (int mt = 0; mt < 4; ++mt)
      #pragma unroll
      for (int r = 0; r < 4; ++r) {
        int c = m0 - 128 + wm * 64 + mt * 16 + quad * 4 + r;
        size_t rowo = ((size_t)b * Cn + c) * Nn + n0;
        #pragma unroll
        for (int nt = 0; nt < 4; ++nt)
          vh[rowo + wn * 64 + nt * 16 + col] = __float2bfloat16(acc[mt][nt][r]);
      }
  } else {
    // ---- Q/K epilogue: transpose 32-n slabs via LDS, pack hi/lo [b][n][64] ----
    float* trs = (float*)smem;           // [32][132]
    #pragma unroll
    for (int p4 = 0; p4 < 4; ++p4) {
      if (wn == (p4 >> 1)) {
        #pragma unroll
        for (int ntl = 0; ntl < 2; ++ntl) {
          int nt = (p4 & 1) * 2 + ntl;
          int nl = ntl * 16 + col;
          #pragma unroll
          for (int mt = 0; mt < 4; ++mt)
            #pragma unroll
            for (int r = 0; r < 4; ++r)
              trs[nl * 132 + wm * 64 + mt * 16 + quad * 4 + r] = acc[mt][nt][r];
        }
      }
      __syncthreads();
      {
        int nl = t >> 3, seg = t & 7;
        float v[16];
        #pragma unroll
        for (int i = 0; i < 16; ++i) v[i] = trs[nl * 132 + seg * 16 + i];
        unsigned short h[16], l[16];
        #pragma unroll
        for (int i = 0; i < 16; ++i) { h[i] = f2b(v[i]); l[i] = f2b(v[i] - b2f_(h[i])); }
        uint4 hu0, hu1, lu0, lu1;
        hu0.x = h[0] | ((unsigned)h[1] << 16);  hu0.y = h[2] | ((unsigned)h[3] << 16);
        hu0.z = h[4] | ((unsigned)h[5] << 16);  hu0.w = h[6] | ((unsigned)h[7] << 16);
        hu1.x = h[8] | ((unsigned)h[9] << 16);  hu1.y = h[10] | ((unsigned)h[11] << 16);
        hu1.z = h[12] | ((unsigned)h[13] << 16); hu1.w = h[14] | ((unsigned)h[15] << 16);
        lu0.x = l[0] | ((unsigned)l[1] << 16);  lu0.y = l[2] | ((unsigned)l[3] << 16);
        lu0.z = l[4] | ((unsigned)l[5] << 16);  lu0.w = l[6] | ((unsigned)l[7] << 16);
        lu1.x = l[8] | ((unsigned)l[9] << 16);  lu1.y = l[10] | ((unsigned)l[11] << 16);
        lu1.z = l[12] | ((unsigned)l[13] << 16); lu1.w = l[14] | ((unsigned)l[15] << 16);
        int n = n0 + p4 * 32 + nl;
        size_t base = ((size_t)b * Nn + n) * 64;
        if (seg < 4) {
          *(uint4*)(qhi + base + seg * 16) = hu0;
          *(uint4*)(qhi + base + seg * 16 + 8) = hu1;
          *(uint4*)(qlo + base + seg * 16) = lu0;
          *(uint4*)(qlo + base + seg * 16 + 8) = lu1;
        } else {
          *(uint4*)(khi + base + (seg - 4) * 16) = hu0;
          *(uint4*)(khi + base + (seg - 4) * 16 + 8) = hu1;
          *(uint4*)(klo + base + (seg - 4) * 16) = lu0;
          *(uint4*)(klo + base + (seg - 4) * 16 + 8) = lu1;
        }
      }
      __syncthreads();
    }
  }
  #undef STAGE
}

// ---------------- MFMA flash attention: producer/consumer waves (R5, 167 us) ----------------
__global__ __launch_bounds__(768, 3) void attn(
    const bf16* __restrict__ qhi_g, const bf16* __restrict__ qlo_g,
    const bf16* __restrict__ khi_g, const bf16* __restrict__ klo_g,
    const bf16* __restrict__ vh, const float* __restrict__ x,
    const float* __restrict__ gamma, float* __restrict__ out) {
  __shared__ bf16 kths[2 * 2 * 32 * 72]; // [buf][hl][j][72]
  __shared__ bf16 pt[2 * 64 * 40];       // [buf][i][j], j-stride 40
  __shared__ float alpha_s[2 * 64];
  __shared__ float lfin[64];

  int t = threadIdx.x;
  int w = t >> 6;
  int lane = t & 63;
  int col = lane & 15;
  int quad = lane >> 4;

  int blk = blockIdx.x;
  int xcd = blk & 7;
  int b = xcd >> 1;
  int itile = ((xcd & 1) << 5) + (blk >> 3);
  int i0 = itile << 6;

  fl4 z = {0.f, 0.f, 0.f, 0.f};

  const bf16* ksrc = (t < 256) ? khi_g : klo_g;
  int hl = (t < 256) ? 0 : 1;
  int ki = t & 255, kj = ki >> 3, koc = ki & 7;
  size_t kgbase = ((size_t)b * Nn + kj) * 64 + koc * 8;
  bf16* kd = kths + hl * 2304 + kj * 72 + koc * 8;
  uint4 kpre;
  if (t < 512) {
    kpre = *(const uint4*)(ksrc + kgbase);
    *(uint4*)kd = kpre;
    kpre = *(const uint4*)(ksrc + kgbase + 32 * 64);
  }

  int it = w;
  short8 qh0, qh1, ql0, ql1;
  float mreg[4], lreg[4];
  if (w < 4) {
    size_t qrow = ((size_t)b * Nn + i0 + it * 16 + col) * 64 + quad * 8;
    qh0 = *(const short8*)(qhi_g + qrow);
    qh1 = *(const short8*)(qhi_g + qrow + 32);
    ql0 = *(const short8*)(qlo_g + qrow);
    ql1 = *(const short8*)(qlo_g + qrow + 32);
    #pragma unroll
    for (int r = 0; r < 4; ++r) { mreg[r] = -3.0e38f; lreg[r] = 0.f; }
  }

  int ow = w - 4, ch0 = ow * 64;
  const bf16* vbase = vh + ((size_t)b * Cn + ch0 + col) * Nn + quad * 8;
  fl4 acc[4][4];
  #pragma unroll
  for (int mt = 0; mt < 4; ++mt)
    #pragma unroll
    for (int nt = 0; nt < 4; ++nt) acc[mt][nt] = z;
  short8 va[4];

  for (int tile = 0; tile < 128; ++tile) {
    __syncthreads();
    int buf = tile & 1;

    if (t < 512) {
      *(uint4*)(kd + (buf ^ 1) * 4608) = kpre;
      int jn = (tile + 2 < 128 ? tile + 2 : 127) << 5;
      kpre = *(const uint4*)(ksrc + kgbase + (size_t)jn * 64);
    }

    if (w < 4) {
      const bf16* kb = kths + buf * 4608;
      const bf16* kbl = kb + 2304;
      short8 khA0 = *(const short8*)(kb + col * 72 + quad * 8);
      short8 khA1 = *(const short8*)(kb + col * 72 + quad * 8 + 32);
      short8 khB0 = *(const short8*)(kb + (16 + col) * 72 + quad * 8);
      short8 khB1 = *(const short8*)(kb + (16 + col) * 72 + quad * 8 + 32);
      short8 klA0 = *(const short8*)(kbl + col * 72 + quad * 8);
      short8 klA1 = *(const short8*)(kbl + col * 72 + quad * 8 + 32);
      short8 klB0 = *(const short8*)(kbl + (16 + col) * 72 + quad * 8);
      short8 klB1 = *(const short8*)(kbl + (16 + col) * 72 + quad * 8 + 32);
      fl4 s0 = MFMA16(qh0, khA0, z);
      fl4 s1 = MFMA16(qh0, khB0, z);
      s0 = MFMA16(qh1, khA1, s0);
      s1 = MFMA16(qh1, khB1, s1);
      s0 = MFMA16(ql0, khA0, s0);
      s1 = MFMA16(ql0, khB0, s1);
      s0 = MFMA16(ql1, khA1, s0);
      s1 = MFMA16(ql1, khB1, s1);
      s0 = MFMA16(qh0, klA0, s0);
      s1 = MFMA16(qh0, klB0, s1);
      s0 = MFMA16(qh1, klA1, s0);
      s1 = MFMA16(qh1, klB1, s1);
      fl4 sA = s0;
      fl4 sB = s1;

      #pragma unroll
      for (int r = 0; r < 4; ++r) {
        float mt_ = fmaxf(sA[r], sB[r]);
        mt_ = fmaxf(mt_, ROR1(mt_)); mt_ = fmaxf(mt_, ROR2(mt_));
        mt_ = fmaxf(mt_, ROR4(mt_)); mt_ = fmaxf(mt_, ROR8(mt_));
        float mnew = fmaxf(mreg[r], mt_);
        float al = __expf(mreg[r] - mnew);
        float pA = __expf(sA[r] - mnew);
        float pB = __expf(sB[r] - mnew);
        float s = pA + pB;
        s += ROR1(s); s += ROR2(s); s += ROR4(s); s += ROR8(s);
        lreg[r] = lreg[r] * al + s;
        mreg[r] = mnew;
        int i = it * 16 + quad * 4 + r;
        pt[buf * 2560 + i * 40 + col] = __float2bfloat16(pA);
        pt[buf * 2560 + i * 40 + 16 + col] = __float2bfloat16(pB);
        if (col == 0) alpha_s[buf * 64 + i] = al;
      }
    } else {
      if (tile > 0) {
        int pb_ = buf ^ 1;
        float av[4];
        #pragma unroll
        for (int nt = 0; nt < 4; ++nt) av[nt] = alpha_s[pb_ * 64 + nt * 16 + col];
        bool nr = (av[0] != 1.f) | (av[1] != 1.f) | (av[2] != 1.f) | (av[3] != 1.f);
        if (__ballot(nr)) {
          #pragma unroll
          for (int mt = 0; mt < 4; ++mt)
            #pragma unroll
            for (int nt = 0; nt < 4; ++nt) acc[mt][nt] *= av[nt];
        }
        short8 pb[4];
        #pragma unroll
        for (int nt = 0; nt < 4; ++nt)
          pb[nt] = *(const short8*)(&pt[pb_ * 2560 + (nt * 16 + col) * 40 + quad * 8]);
        #pragma unroll
        for (int nt = 0; nt < 4; ++nt) {
          acc[0][nt] = MFMA16(va[0], pb[nt], acc[0][nt]);
          acc[1][nt] = MFMA16(va[1], pb[nt], acc[1][nt]);
          acc[2][nt] = MFMA16(va[2], pb[nt], acc[2][nt]);
          acc[3][nt] = MFMA16(va[3], pb[nt], acc[3][nt]);
        }
      }
      const bf16* vj = vbase + (tile << 5);
      va[0] = *(const short8*)(vj);
      va[1] = *(const short8*)(vj + (size_t)16 * Nn);
      va[2] = *(const short8*)(vj + (size_t)32 * Nn);
      va[3] = *(const short8*)(vj + (size_t)48 * Nn);
    }
  }

  if (w < 4 && col == 0) {
    #pragma unroll
    for (int r = 0; r < 4; ++r) lfin[it * 16 + quad * 4 + r] = lreg[r];
  }
  __syncthreads();

  if (w >= 4) {
    float av[4];
    #pragma unroll
    for (int nt = 0; nt < 4; ++nt) av[nt] = alpha_s[64 + nt * 16 + col];
    bool nr = (av[0] != 1.f) | (av[1] != 1.f) | (av[2] != 1.f) | (av[3] != 1.f);
    if (__ballot(nr)) {
      #pragma unroll
      for (int mt = 0; mt < 4; ++mt)
        #pragma unroll
        for (int nt = 0; nt < 4; ++nt) acc[mt][nt] *= av[nt];
    }
    short8 pb[4];
    #pragma unroll
    for (int nt = 0; nt < 4; ++nt)
      pb[nt] = *(const short8*)(&pt[2560 + (nt * 16 + col) * 40 + quad * 8]);
    #pragma unroll
    for (int nt = 0; nt < 4; ++nt) {
      acc[0][nt] = MFMA16(va[0], pb[nt], acc[0][nt]);
      acc[1][nt] = MFMA16(va[1], pb[nt], acc[1][nt]);
      acc[2][nt] = MFMA16(va[2], pb[nt], acc[2][nt]);
      acc[3][nt] = MFMA16(va[3], pb[nt], acc[3][nt]);
    }

    float gm = gamma[0];
    float linv[4];
    #pragma unroll
    for (int nt = 0; nt < 4; ++nt) linv[nt] = 1.f / lfin[nt * 16 + col];
    #pragma unroll
    for (int mt = 0; mt < 4; ++mt) {
      int c = ch0 + mt * 16 + quad * 4;
      #pragma unroll
      for (int r = 0; r < 4; ++r) {
        size_t rowoff = ((size_t)b * Cn + c + r) * Nn + i0;
        #pragma unroll
        for (int nt = 0; nt < 4; ++nt) {
          size_t off = rowoff + nt * 16 + col;
          out[off] = gm * (acc[mt][nt][r] * linv[nt]) + x[off];
        }
      }
    }
  }
}

extern "C" void kernel_launch(void* const* d_in, const int* in_sizes, int n_in,
                              void* d_out, int out_size, void* d_ws, size_t ws_size,
                              hipStream_t stream) {
  const float* x     = (const float*)d_in[0];
  const float* Wq    = (const float*)d_in[1];
  const float* bq    = (const float*)d_in[2];
  const float* Wk    = (const float*)d_in[3];
  const float* bk    = (const float*)d_in[4];
  const float* Wv    = (const float*)d_in[5];
  const float* bv    = (const float*)d_in[6];
  const float* gamma = (const float*)d_in[7];
  float* out = (float*)d_out;

  size_t qkN = (size_t)Bn * Nn * 64;            // 1M elems = 2 MB each
  bf16* qhi = (bf16*)d_ws;
  bf16* qlo = qhi + qkN;
  bf16* khi = qlo + qkN;
  bf16* klo = khi + qkN;
  bf16* vh  = klo + qkN;                        // 16 MB
  bf16* whi = vh + (size_t)Bn * Cn * Nn;        // 640 KB
  bf16* wlo = whi + (size_t)640 * Cn;           // 640 KB (MUST be contiguous after whi)
  float* bcat = (float*)(wlo + (size_t)640 * Cn);

  // x^T hi/lo lives in d_out (32 MB exactly); attn overwrites d_out last.
  bf16* xth = (bf16*)d_out;
  bf16* xtl = xth + (size_t)Bn * Nn * Cn;       // +16 MB (constant offset used in-kernel)

  prep_w<<<dim3(640), dim3(128), 0, stream>>>(Wq, bq, Wk, bk, Wv, bv, whi, wlo, bcat);
  prep_x<<<dim3(8192), dim3(256), 0, stream>>>(x, xth, xtl);
  qkv_gemm<<<dim3(640), dim3(256), 0, stream>>>(whi, bcat, xth,
                                                qhi, qlo, khi, klo, vh);
  attn<<<dim3(256), dim3(768), 0, stream>>>(qhi, qlo, khi, klo, vh, x, gamma, out);
}